// Round 5
// baseline (193.303 us; speedup 1.0000x reference)
//
#include <hip/hip_runtime.h>

// ONN conv2d: B=16, Cin=128, H=W=32, Cout=256, k=3 (pad=1, stride=1)
// N=16384 positions, D=1152=18*64 chunks of VEC=64, M=256.
// out[n,m] = sum_r sign01( dot_c( x[n,64r+c], wq[64r+c,m] ) )
// wq = clamp(rintf(w*scale), -7, 7), scale = fl32(15/(fl32(max-min)+1e-9f))
//
// Main path: bf16 MFMA with x split hi/lo (w int4 exact in bf16).
// |mfma_dot - ref_fp32_chain| < ~2e-3; dots with |s| < TAU=0.03 recomputed
// bit-exactly (sequential fp32, ascending c, separate mul/add -- R4 body).
// R3->R4: per-dot global atomics -> per-block LDS queue (611 -> 93 us).
// R5 FAILED: rewritten k_fix body flipped a sign; reverted (proven R4 body).
// R6: k_fix grid 64->512. R7: barrier-free gather k_main.
// R8: depth-1 B prefetch + fix folded into tail (64.3 us k_main).
// R9 FAILED (101 us): split-K GLOBAL atomics blew HBM; bounds squeezed regs.
// R10: branchless hot chunk, one cold handler/chunk (63.0 us; VGPR 64).
// R11: 128m/wave amortization + sign-VALU trim; grid (256,2) starved
//      occupancy (2 waves/SIMD) -> 73 us despite VALUBusy 47->25.
// R12: in-block 2-way split-K (512 thr = 4nt x 2kz, LDS merge): 52.7 us.
//      VGPR 64, Occ 26.6 (grid caps at 16 waves/CU), VALUBusy 30 -- still
//      ~60% idle; wave count (4096) is the binding constraint.
// R13: 3-way in-block split-K (18 = 3x6): 768 thr = 12 waves = 4nt x 3kz,
//      6 chunks/wave. Same total per-chunk work, 6144 waves, 24 waves/CU
//      cap (6/SIMD). Merge: kz=1,2 deposit byte-packed counts (<=6) in
//      red_s[2][..]; kz=0 adds both. launch_bounds(768,6) (VGPR cap 84,
//      natural 64). LDS ~31KB/block, 2 blocks/CU = 63KB ok.

#define TAU 0.03f
#define HITCAP 2048

typedef short short8 __attribute__((ext_vector_type(8)));
typedef float f32x4 __attribute__((ext_vector_type(4)));
typedef unsigned int uv4 __attribute__((ext_vector_type(4)));

__device__ __forceinline__ unsigned short bf16rn(float v) {
    unsigned u = __float_as_uint(v);
    unsigned r = u + 0x7fffu + ((u >> 16) & 1u);
    return (unsigned short)(r >> 16);
}

// ---------------- prep: weight min/max partials (blocks 0..63) +
//                  zero-padded hi/lo bf16 planes (blocks 64..2111) ----------------
__global__ __launch_bounds__(256) void k_prep(const float* __restrict__ w,
                                              const float* __restrict__ inp,
                                              float* __restrict__ pmin,
                                              float* __restrict__ pmax,
                                              unsigned* __restrict__ xpk) {
    if (blockIdx.x < 64) {
        int tid = blockIdx.x * 256 + threadIdx.x;
        float vmin = 1e30f, vmax = -1e30f;
        for (int i = tid; i < 294912; i += 64 * 256) {
            float v = w[i];
            vmin = fminf(vmin, v);
            vmax = fmaxf(vmax, v);
        }
        #pragma unroll
        for (int off = 32; off > 0; off >>= 1) {
            vmin = fminf(vmin, __shfl_down(vmin, off, 64));
            vmax = fmaxf(vmax, __shfl_down(vmax, off, 64));
        }
        __shared__ float smin[4], smax[4];
        int wave = threadIdx.x >> 6;
        if ((threadIdx.x & 63) == 0) { smin[wave] = vmin; smax[wave] = vmax; }
        __syncthreads();
        if (threadIdx.x == 0) {
            #pragma unroll
            for (int i = 1; i < 4; i++) {
                vmin = fminf(vmin, smin[i]);
                vmax = fmaxf(vmax, smax[i]);
            }
            pmin[blockIdx.x] = vmin;
            pmax[blockIdx.x] = vmax;
        }
    } else {
        int bc = blockIdx.x - 64;              // b*128 + cin (2048)
        const float* src = inp + (size_t)bc * 1024;
        unsigned* dst = xpk + (size_t)bc * 1156;
        #pragma unroll
        for (int i = 0; i < 5; ++i) {
            int idx = threadIdx.x + i * 256;
            if (idx < 1156) {
                int yy = idx / 34, xx = idx - yy * 34;
                float v = 0.0f;
                int ys = yy - 1, xs_ = xx - 1;
                if ((unsigned)ys < 32u && (unsigned)xs_ < 32u) v = src[ys * 32 + xs_];
                unsigned short h = bf16rn(v);
                float hf = __uint_as_float((unsigned)h << 16);
                unsigned short l = bf16rn(v - hf);
                dst[idx] = (unsigned)h | ((unsigned)l << 16);
            }
        }
    }
}

// block-local scale from the 64 partials (identical fp32 op sequence everywhere)
__device__ __forceinline__ float block_scale(const float* pmin, const float* pmax,
                                             float* sca_lds) {
    int t = threadIdx.x;
    if (t < 64) {
        float vmin = pmin[t];
        float vmax = pmax[t];
        #pragma unroll
        for (int off = 32; off > 0; off >>= 1) {
            vmin = fminf(vmin, __shfl_down(vmin, off, 64));
            vmax = fmaxf(vmax, __shfl_down(vmax, off, 64));
        }
        if (t == 0) {
            float tt = __fadd_rn(__fsub_rn(vmax, vmin), 1e-9f);
            *sca_lds = __fdiv_rn(15.0f, tt);
        }
    }
    __syncthreads();
    return *sca_lds;
}

// ---------------- prep: quantize weights into MFMA A-fragment order ----------------
// slot = ((g*18 + r)*8 + mt*2 + khalf)*64 + lane ; 16B per slot (8 bf16, k ascending)
// value(lane, j) = wq[d = 64r + khalf*32 + (lane>>4)*8 + j][m = g*64 + mt*16 + (lane&15)]
__global__ __launch_bounds__(256) void k_quantb(const float* __restrict__ w,
                                                const float* __restrict__ pmin,
                                                const float* __restrict__ pmax,
                                                uv4* __restrict__ wqb) {
    __shared__ float sca;
    float s = block_scale(pmin, pmax, &sca);
    int slot = blockIdx.x * 256 + threadIdx.x;   // 36864 total
    int lane = slot & 63;
    int sub = slot >> 6;
    int khalf = sub & 1;
    int mt = (sub >> 1) & 3;
    int gr = sub >> 3;                 // g*18 + r
    int g = gr / 18, r = gr - g * 18;
    int m = g * 64 + mt * 16 + (lane & 15);
    int dbase = r * 64 + khalf * 32 + (lane >> 4) * 8;
    const float* wp = w + (size_t)m * 1152 + dbase;
    unsigned o[4];
    #pragma unroll
    for (int p = 0; p < 4; ++p) {
        float q0 = rintf(__fmul_rn(wp[2 * p], s));
        float q1 = rintf(__fmul_rn(wp[2 * p + 1], s));
        q0 = fminf(fmaxf(q0, -7.0f), 7.0f);
        q1 = fminf(fmaxf(q1, -7.0f), 7.0f);
        o[p] = (unsigned)bf16rn(q0) | ((unsigned)bf16rn(q1) << 16);
    }
    uv4 v; v.x = o[0]; v.y = o[1]; v.z = o[2]; v.w = o[3];
    wqb[slot] = v;
}

// gather: uniform SGPR base + per-lane 32-bit byte offset (xdelta + plane ofs)
#define XLD(o) (*reinterpret_cast<const unsigned*>(xpkB + (xdelta + (unsigned)(o))))

// issue the 16 B-gather u32 loads for chunk rr into dst[16]
// (byte offsets via 4x ds_read_b128; q2<8 -> khalf0, q2>=8 -> khalf1)
#define ISSUE_B(rr, dst) do {                                                  \
    const int4* _oa = reinterpret_cast<const int4*>(&ofs_s[(rr) * 64 + quad * 8]); \
    int4 _o0 = _oa[0], _o1 = _oa[1];                                           \
    const int4* _ob = reinterpret_cast<const int4*>(&ofs_s[(rr) * 64 + 32 + quad * 8]); \
    int4 _o2 = _ob[0], _o3 = _ob[1];                                           \
    dst[0] = XLD(_o0.x); dst[1] = XLD(_o0.y); dst[2] = XLD(_o0.z); dst[3] = XLD(_o0.w); \
    dst[4] = XLD(_o1.x); dst[5] = XLD(_o1.y); dst[6] = XLD(_o1.z); dst[7] = XLD(_o1.w); \
    dst[8] = XLD(_o2.x); dst[9] = XLD(_o2.y); dst[10] = XLD(_o2.z); dst[11] = XLD(_o2.w); \
    dst[12] = XLD(_o3.x); dst[13] = XLD(_o3.y); dst[14] = XLD(_o3.z); dst[15] = XLD(_o3.w); \
} while (0)

// A-fragment slot index for (chunk rr, m-tile mm) at this lane (mm in 0..7;
// wqb layout has 4 original g-groups of 4 mt, our 128m half spans 2 groups)
#define AIDX(rr, mm) ((((mm) >> 2) * 9216) + (rr) * 512 + (((mm) & 3) * 128))

// ---------------- main: 3-way in-block split-K gather GEMM (768 thr) + fix ----------
// 12 waves = 4 n-tiles x 3 kz thirds; each wave: 16n x 128m x 6 chunks.
// kz=1,2 waves deposit packed negcnt in LDS; kz=0 waves merge + store.
__global__ __launch_bounds__(768, 6) void k_main(const unsigned* __restrict__ xpk,
                                                 const uv4* __restrict__ wqb,
                                                 const float* __restrict__ inp,
                                                 const float* __restrict__ weight,
                                                 const float* __restrict__ pmin,
                                                 const float* __restrict__ pmax,
                                                 float* __restrict__ out) {
    __shared__ alignas(16) int ofs_s[1152]; // BYTE plane offset per k: (cin*1156+kh*34+kw)*4
    __shared__ unsigned hitbuf[HITCAP];
    __shared__ unsigned red_s[2][4][64][9]; // [kz-1][nt][lane][mt] packed bytes
    __shared__ unsigned hitcnt;
    __shared__ float sca;

    const int t = threadIdx.x;
    if (t == 0) hitcnt = 0u;
    float sc = block_scale(pmin, pmax, &sca);   // also covers the hitcnt init barrier
    for (int k = t; k < 1152; k += 768) {
        int cin = k / 9;
        int rem = k - cin * 9;
        int kh = rem / 3;
        int kw = rem - kh * 3;
        ofs_s[k] = (cin * 1156 + kh * 34 + kw) * 4;
    }
    __syncthreads();

    const int lane = t & 63;
    const int wv12 = t >> 6;           // 0..11
    const int nt = wv12 & 3;           // n-tile 0..3
    const int kz = wv12 >> 2;          // K third: chunks [kz*6, kz*6+6)
    const int quad = lane >> 4;
    const int nl = lane & 15;
    const int n0 = blockIdx.x * 64;
    const int g = blockIdx.y;          // 128-m half: m in [g*128, g*128+128)
    const int b = n0 >> 10;
    const int r0 = kz * 6, rend = r0 + 6;

    // wave's image-position base (16 consecutive positions within one row)
    const int sy_w = ((n0 & 1023) >> 5) + (nt >> 1);
    const int col0 = (nt & 1) * 16;
    const char* __restrict__ xpkB = (const char*)xpk;   // uniform base (SGPR)
    const unsigned xdelta =
        ((unsigned)b * (128u * 1156u) + (unsigned)(sy_w * 34 + col0 + nl)) * 4u;
    const uv4* __restrict__ aw = wqb + (size_t)g * (2 * 18 * 512) + lane;

    // negcnt packed: [mt][pair] u32, two 16-bit counters (i=2p lo, i=2p+1 hi)
    unsigned negpk[8][2] = {};
    unsigned long long hitacc = 0ull;

    // ---- prologue: prefetch chunk r0's B-gather u32s and (r0, mt0) A-frags ----
    unsigned pb[16];
    ISSUE_B(r0, pb);
    short8 ac0 = __builtin_bit_cast(short8, aw[AIDX(r0, 0)]);
    short8 ac1 = __builtin_bit_cast(short8, aw[AIDX(r0, 0) + 64]);

    for (int r = r0; r < rend; ++r) {
        // ---- repack current B (split packed hi|lo) via v_perm_b32 ----
        short8 bhi[2], blo[2];
        #pragma unroll
        for (int kh2 = 0; kh2 < 2; ++kh2) {
            union { unsigned d[4]; short8 v; } H, L;
            #pragma unroll
            for (int p = 0; p < 4; ++p) {
                unsigned ua = pb[kh2 * 8 + 2 * p], ub = pb[kh2 * 8 + 2 * p + 1];
                H.d[p] = __builtin_amdgcn_perm(ub, ua, 0x05040100u); // ua.lo | ub.lo<<16
                L.d[p] = __builtin_amdgcn_perm(ub, ua, 0x07060302u); // ua.hi | ub.hi<<16
            }
            bhi[kh2] = H.v;
            blo[kh2] = L.v;
        }

        // issue next chunk's gathers, branchless (last r harmlessly reloads)
        const int rn = (r + 1 < rend) ? r + 1 : r;
        ISSUE_B(rn, pb);

        // ---- 8 m-tiles, fully branchless; rolling depth-1 A-pair prefetch ----
        f32x4 accs[8];
        #pragma unroll
        for (int mt = 0; mt < 8; ++mt) {
            const int pn = (mt == 7) ? AIDX(rn, 0) : AIDX(r, mt + 1);
            short8 an0 = __builtin_bit_cast(short8, aw[pn]);
            short8 an1 = __builtin_bit_cast(short8, aw[pn + 64]);

            f32x4 acc = {0.0f, 0.0f, 0.0f, 0.0f};
            acc = __builtin_amdgcn_mfma_f32_16x16x32_bf16(ac0, bhi[0], acc, 0, 0, 0);
            acc = __builtin_amdgcn_mfma_f32_16x16x32_bf16(ac1, bhi[1], acc, 0, 0, 0);
            acc = __builtin_amdgcn_mfma_f32_16x16x32_bf16(ac0, blo[0], acc, 0, 0, 0);
            acc = __builtin_amdgcn_mfma_f32_16x16x32_bf16(ac1, blo[1], acc, 0, 0, 0);
            accs[mt] = acc;
            #pragma unroll
            for (int p = 0; p < 2; ++p) {
                unsigned sb0 = __float_as_uint(acc[2 * p]) >> 31;
                unsigned sb1 = __float_as_uint(acc[2 * p + 1]) >> 31;
                negpk[mt][p] += sb0 + (sb1 << 16);
                hitacc |= __ballot(__builtin_fabsf(acc[2 * p]) < TAU);
                hitacc |= __ballot(__builtin_fabsf(acc[2 * p + 1]) < TAU);
            }
            ac0 = an0;
            ac1 = an1;
        }

        // ---- one rare cold branch per chunk: queue hits (per-lane id rebuilt) ----
        if (hitacc) {
            #pragma unroll
            for (int mt = 0; mt < 8; ++mt)
                #pragma unroll
                for (int i = 0; i < 4; ++i) {
                    float s = accs[mt][i];
                    if (__builtin_fabsf(s) < TAU) {
                        unsigned ge = (__float_as_uint(s) >> 31) ^ 1u;   // match negpk
                        unsigned idx = atomicAdd(&hitcnt, 1u);           // LDS atomic: rare
                        if (idx < (unsigned)HITCAP) {
                            unsigned m = (unsigned)(g * 128 + mt * 16 + quad * 4 + i);
                            unsigned n = (unsigned)(n0 + nt * 16 + nl);
                            hitbuf[idx] = n | ((unsigned)r << 14) | (m << 19)
                                            | (ge << 27);
                        }
                    }
                }
            hitacc = 0ull;
        }
    }

    // ---- merge kz thirds via LDS; kz=0 waves store final counts ----
    if (kz != 0) {
        #pragma unroll
        for (int mt = 0; mt < 8; ++mt) {
            unsigned c0 = negpk[mt][0] & 0xffffu, c1 = negpk[mt][0] >> 16;
            unsigned c2 = negpk[mt][1] & 0xffffu, c3 = negpk[mt][1] >> 16;
            red_s[kz - 1][nt][lane][mt] = c0 | (c1 << 8) | (c2 << 16) | (c3 << 24);
        }
    }
    __syncthreads();
    if (kz == 0) {
        const int n = n0 + nt * 16 + nl;
        const int p = n & 1023;
        #pragma unroll
        for (int mt = 0; mt < 8; ++mt) {
            unsigned pk1 = red_s[0][nt][lane][mt];
            unsigned pk2 = red_s[1][nt][lane][mt];
            unsigned tot0 = (negpk[mt][0] & 0xffffu) + (pk1 & 255u) + (pk2 & 255u);
            unsigned tot1 = (negpk[mt][0] >> 16) + ((pk1 >> 8) & 255u) + ((pk2 >> 8) & 255u);
            unsigned tot2 = (negpk[mt][1] & 0xffffu) + ((pk1 >> 16) & 255u) + ((pk2 >> 16) & 255u);
            unsigned tot3 = (negpk[mt][1] >> 16) + (pk1 >> 24) + (pk2 >> 24);
            int mb = g * 128 + mt * 16 + quad * 4;
            size_t obase = ((size_t)(b * 256 + mb)) << 10;
            out[obase + p]                = (float)(18u - tot0);
            out[obase + (1ull << 10) + p] = (float)(18u - tot1);
            out[obase + (2ull << 10) + p] = (float)(18u - tot2);
            out[obase + (3ull << 10) + p] = (float)(18u - tot3);
        }
    }

    // ---- in-block fixup of this block's own hits (R4 k_fix body, verbatim math) ----
    __syncthreads();
    unsigned tot = hitcnt;
    if (tot > (unsigned)HITCAP) tot = (unsigned)HITCAP;
    for (unsigned i = t; i < tot; i += 768) {
        unsigned u = hitbuf[i];
        int n = u & 16383;
        int r = (u >> 14) & 31;
        int m = (u >> 19) & 255;
        int bit = (u >> 27) & 1;
        int bb = n >> 10, p = n & 1023, y = p >> 5, x = p & 31;
        const float* ib = inp + (size_t)bb * (128 * 32 * 32);
        const float* wp = weight + (size_t)m * 1152;
        float s = 0.0f;
        int d = r * 64;
        for (int c = 0; c < 64; ++c, ++d) {
            int ci = d / 9, rem = d - ci * 9;
            int kh = rem / 3, kw = rem - kh * 3;
            int yy = y + kh - 1, xx = x + kw - 1;
            float xv = 0.0f;
            if ((unsigned)yy < 32u && (unsigned)xx < 32u)
                xv = ib[(ci * 32 + yy) * 32 + xx];
            float q = rintf(__fmul_rn(wp[d], sc));
            q = fminf(fmaxf(q, -7.0f), 7.0f);
            s = __fadd_rn(s, __fmul_rn(xv, q));
        }
        int nb = (s >= 0.0f) ? 1 : 0;
        if (nb != bit)
            atomicAdd(&out[(((size_t)(bb * 256 + m)) << 10) + p], nb ? 1.0f : -1.0f);
    }
}

extern "C" void kernel_launch(void* const* d_in, const int* in_sizes, int n_in,
                              void* d_out, int out_size, void* d_ws, size_t ws_size,
                              hipStream_t stream) {
    const float* inp    = (const float*)d_in[0];   // [16,128,32,32]
    const float* weight = (const float*)d_in[1];   // [256,128,3,3]
    float* out = (float*)d_out;                    // [16,256,32,32]

    char* ws = (char*)d_ws;
    float*    pmin  = (float*)(ws + 0);
    float*    pmax  = (float*)(ws + 256);
    uv4*      wqb   = (uv4*)(ws + 1024);          // 589,824 B
    unsigned* xpk   = (unsigned*)(ws + 590848);   // 9,469,952 B

    k_prep<<<2112, 256, 0, stream>>>(weight, inp, pmin, pmax, xpk);
    k_quantb<<<144, 256, 0, stream>>>(weight, pmin, pmax, wqb);

    dim3 grid(256, 2);   // (N/64, M/128); 768-thread blocks, 3-way split-K in-block
    k_main<<<grid, 768, 0, stream>>>(xpk, wqb, inp, weight, pmin, pmax, out);
}

// Round 6
// 140.611 us; speedup vs baseline: 1.3747x; 1.3747x over previous
//
#include <hip/hip_runtime.h>

// ONN conv2d: B=16, Cin=128, H=W=32, Cout=256, k=3 (pad=1, stride=1)
// N=16384 positions, D=1152=18*64 chunks of VEC=64, M=256.
// out[n,m] = sum_r sign01( dot_c( x[n,64r+c], wq[64r+c,m] ) )
// wq = clamp(rintf(w*scale), -7, 7), scale = fl32(15/(fl32(max-min)+1e-9f))
//
// Main path: bf16 MFMA with x split hi/lo (w int4 exact in bf16).
// |mfma_dot - ref_fp32_chain| < ~2e-3; dots with |s| < TAU=0.03 recomputed
// bit-exactly (sequential fp32, ascending c, separate mul/add -- R4 body).
// R3->R4: per-dot global atomics -> per-block LDS queue (611 -> 93 us).
// R5 FAILED: rewritten k_fix body flipped a sign; reverted (proven R4 body).
// R6: k_fix grid 64->512. R7: barrier-free gather k_main.
// R8: depth-1 B prefetch + fix folded into tail (64.3 us k_main).
// R9 FAILED (101 us): split-K GLOBAL atomics blew HBM; bounds squeezed regs.
// R10: branchless hot chunk, one cold handler/chunk (63.0 us; VGPR 64).
// R11: 128m/wave amortization + sign-VALU trim; grid (256,2) starved
//      occupancy (2 waves/SIMD) -> 73 us despite VALUBusy 47->25.
// R12: in-block 2-way split-K (512 thr = 4nt x 2kz, LDS merge): 52.7 us.
//      VGPR 64, Occ 26.6 (grid caps at 16 waves/CU) -- wave count binds.
// R13 FAILED (122 us): launch_bounds(768,6) drove VGPR to 40 -> accs/pb
//      spilled to scratch: WRITE 17->294 MB, FETCH 25->164 MB, HBM-bound
//      on spill traffic. 3-way-split concept untested; bound poisoned it.
// R14: occupancy lever with PROVEN register config: keep 512-thr blocks +
//      launch_bounds(512,4) (VGPR=64, no spill in R12); get waves from
//      the grid: 2 nt x 4 kz quarters (18=5+5+4+4), grid (512,2) = 1024
//      blocks = 4 blk/CU x 8 waves = 32 waves/CU cap (2x R12). Merge: 3
//      depositing quarters, byte-packed (counts<=5). LDS ~26.7 KB -> 4
//      blocks/CU = 107 KB ok. Hot loop / hit queue / R4 fix verbatim.

#define TAU 0.03f
#define HITCAP 2048

typedef short short8 __attribute__((ext_vector_type(8)));
typedef float f32x4 __attribute__((ext_vector_type(4)));
typedef unsigned int uv4 __attribute__((ext_vector_type(4)));

__device__ __forceinline__ unsigned short bf16rn(float v) {
    unsigned u = __float_as_uint(v);
    unsigned r = u + 0x7fffu + ((u >> 16) & 1u);
    return (unsigned short)(r >> 16);
}

// ---------------- prep: weight min/max partials (blocks 0..63) +
//                  zero-padded hi/lo bf16 planes (blocks 64..2111) ----------------
__global__ __launch_bounds__(256) void k_prep(const float* __restrict__ w,
                                              const float* __restrict__ inp,
                                              float* __restrict__ pmin,
                                              float* __restrict__ pmax,
                                              unsigned* __restrict__ xpk) {
    if (blockIdx.x < 64) {
        int tid = blockIdx.x * 256 + threadIdx.x;
        float vmin = 1e30f, vmax = -1e30f;
        for (int i = tid; i < 294912; i += 64 * 256) {
            float v = w[i];
            vmin = fminf(vmin, v);
            vmax = fmaxf(vmax, v);
        }
        #pragma unroll
        for (int off = 32; off > 0; off >>= 1) {
            vmin = fminf(vmin, __shfl_down(vmin, off, 64));
            vmax = fmaxf(vmax, __shfl_down(vmax, off, 64));
        }
        __shared__ float smin[4], smax[4];
        int wave = threadIdx.x >> 6;
        if ((threadIdx.x & 63) == 0) { smin[wave] = vmin; smax[wave] = vmax; }
        __syncthreads();
        if (threadIdx.x == 0) {
            #pragma unroll
            for (int i = 1; i < 4; i++) {
                vmin = fminf(vmin, smin[i]);
                vmax = fmaxf(vmax, smax[i]);
            }
            pmin[blockIdx.x] = vmin;
            pmax[blockIdx.x] = vmax;
        }
    } else {
        int bc = blockIdx.x - 64;              // b*128 + cin (2048)
        const float* src = inp + (size_t)bc * 1024;
        unsigned* dst = xpk + (size_t)bc * 1156;
        #pragma unroll
        for (int i = 0; i < 5; ++i) {
            int idx = threadIdx.x + i * 256;
            if (idx < 1156) {
                int yy = idx / 34, xx = idx - yy * 34;
                float v = 0.0f;
                int ys = yy - 1, xs_ = xx - 1;
                if ((unsigned)ys < 32u && (unsigned)xs_ < 32u) v = src[ys * 32 + xs_];
                unsigned short h = bf16rn(v);
                float hf = __uint_as_float((unsigned)h << 16);
                unsigned short l = bf16rn(v - hf);
                dst[idx] = (unsigned)h | ((unsigned)l << 16);
            }
        }
    }
}

// block-local scale from the 64 partials (identical fp32 op sequence everywhere)
__device__ __forceinline__ float block_scale(const float* pmin, const float* pmax,
                                             float* sca_lds) {
    int t = threadIdx.x;
    if (t < 64) {
        float vmin = pmin[t];
        float vmax = pmax[t];
        #pragma unroll
        for (int off = 32; off > 0; off >>= 1) {
            vmin = fminf(vmin, __shfl_down(vmin, off, 64));
            vmax = fmaxf(vmax, __shfl_down(vmax, off, 64));
        }
        if (t == 0) {
            float tt = __fadd_rn(__fsub_rn(vmax, vmin), 1e-9f);
            *sca_lds = __fdiv_rn(15.0f, tt);
        }
    }
    __syncthreads();
    return *sca_lds;
}

// ---------------- prep: quantize weights into MFMA A-fragment order ----------------
// slot = ((g*18 + r)*8 + mt*2 + khalf)*64 + lane ; 16B per slot (8 bf16, k ascending)
// value(lane, j) = wq[d = 64r + khalf*32 + (lane>>4)*8 + j][m = g*64 + mt*16 + (lane&15)]
__global__ __launch_bounds__(256) void k_quantb(const float* __restrict__ w,
                                                const float* __restrict__ pmin,
                                                const float* __restrict__ pmax,
                                                uv4* __restrict__ wqb) {
    __shared__ float sca;
    float s = block_scale(pmin, pmax, &sca);
    int slot = blockIdx.x * 256 + threadIdx.x;   // 36864 total
    int lane = slot & 63;
    int sub = slot >> 6;
    int khalf = sub & 1;
    int mt = (sub >> 1) & 3;
    int gr = sub >> 3;                 // g*18 + r
    int g = gr / 18, r = gr - g * 18;
    int m = g * 64 + mt * 16 + (lane & 15);
    int dbase = r * 64 + khalf * 32 + (lane >> 4) * 8;
    const float* wp = w + (size_t)m * 1152 + dbase;
    unsigned o[4];
    #pragma unroll
    for (int p = 0; p < 4; ++p) {
        float q0 = rintf(__fmul_rn(wp[2 * p], s));
        float q1 = rintf(__fmul_rn(wp[2 * p + 1], s));
        q0 = fminf(fmaxf(q0, -7.0f), 7.0f);
        q1 = fminf(fmaxf(q1, -7.0f), 7.0f);
        o[p] = (unsigned)bf16rn(q0) | ((unsigned)bf16rn(q1) << 16);
    }
    uv4 v; v.x = o[0]; v.y = o[1]; v.z = o[2]; v.w = o[3];
    wqb[slot] = v;
}

// gather: uniform SGPR base + per-lane 32-bit byte offset (xdelta + plane ofs)
#define XLD(o) (*reinterpret_cast<const unsigned*>(xpkB + (xdelta + (unsigned)(o))))

// issue the 16 B-gather u32 loads for chunk rr into dst[16]
// (byte offsets via 4x ds_read_b128; q2<8 -> khalf0, q2>=8 -> khalf1)
#define ISSUE_B(rr, dst) do {                                                  \
    const int4* _oa = reinterpret_cast<const int4*>(&ofs_s[(rr) * 64 + quad * 8]); \
    int4 _o0 = _oa[0], _o1 = _oa[1];                                           \
    const int4* _ob = reinterpret_cast<const int4*>(&ofs_s[(rr) * 64 + 32 + quad * 8]); \
    int4 _o2 = _ob[0], _o3 = _ob[1];                                           \
    dst[0] = XLD(_o0.x); dst[1] = XLD(_o0.y); dst[2] = XLD(_o0.z); dst[3] = XLD(_o0.w); \
    dst[4] = XLD(_o1.x); dst[5] = XLD(_o1.y); dst[6] = XLD(_o1.z); dst[7] = XLD(_o1.w); \
    dst[8] = XLD(_o2.x); dst[9] = XLD(_o2.y); dst[10] = XLD(_o2.z); dst[11] = XLD(_o2.w); \
    dst[12] = XLD(_o3.x); dst[13] = XLD(_o3.y); dst[14] = XLD(_o3.z); dst[15] = XLD(_o3.w); \
} while (0)

// A-fragment slot index for (chunk rr, m-tile mm) at this lane (mm in 0..7;
// wqb layout has 4 original g-groups of 4 mt, our 128m half spans 2 groups)
#define AIDX(rr, mm) ((((mm) >> 2) * 9216) + (rr) * 512 + (((mm) & 3) * 128))

// ---------------- main: 4-way in-block split-K gather GEMM (512 thr) + fix ----------
// 8 waves = 2 n-tiles x 4 kz quarters (chunks 5+5+4+4); each wave: 16n x 128m.
// kz=1..3 waves deposit packed negcnt in LDS; kz=0 waves merge + store.
__global__ __launch_bounds__(512, 4) void k_main(const unsigned* __restrict__ xpk,
                                                 const uv4* __restrict__ wqb,
                                                 const float* __restrict__ inp,
                                                 const float* __restrict__ weight,
                                                 const float* __restrict__ pmin,
                                                 const float* __restrict__ pmax,
                                                 float* __restrict__ out) {
    __shared__ alignas(16) int ofs_s[1152]; // BYTE plane offset per k: (cin*1156+kh*34+kw)*4
    __shared__ unsigned hitbuf[HITCAP];
    __shared__ unsigned red_s[3][2][64][9]; // [kz-1][nt][lane][mt] packed bytes
    __shared__ unsigned hitcnt;
    __shared__ float sca;

    const int t = threadIdx.x;
    if (t == 0) hitcnt = 0u;
    float sc = block_scale(pmin, pmax, &sca);   // also covers the hitcnt init barrier
    for (int k = t; k < 1152; k += 512) {
        int cin = k / 9;
        int rem = k - cin * 9;
        int kh = rem / 3;
        int kw = rem - kh * 3;
        ofs_s[k] = (cin * 1156 + kh * 34 + kw) * 4;
    }
    __syncthreads();

    const int lane = t & 63;
    const int wv8 = t >> 6;            // 0..7
    const int nt = wv8 & 1;            // n-tile 0..1
    const int kz = wv8 >> 1;           // K quarter 0..3: chunks {0-5,5-10,10-14,14-18}
    const int quad = lane >> 4;
    const int nl = lane & 15;
    const int n0 = blockIdx.x * 32;
    const int g = blockIdx.y;          // 128-m half: m in [g*128, g*128+128)
    const int b = n0 >> 10;
    const int r0 = kz * 5 - ((kz > 2) ? (kz - 2) : 0);
    const int rend = r0 + ((kz < 2) ? 5 : 4);

    // wave's image-position base (16 consecutive positions within one row;
    // 32 n per block = exactly one image row)
    const int sy_w = (n0 & 1023) >> 5;
    const int col0 = nt * 16;
    const char* __restrict__ xpkB = (const char*)xpk;   // uniform base (SGPR)
    const unsigned xdelta =
        ((unsigned)b * (128u * 1156u) + (unsigned)(sy_w * 34 + col0 + nl)) * 4u;
    const uv4* __restrict__ aw = wqb + (size_t)g * (2 * 18 * 512) + lane;

    // negcnt packed: [mt][pair] u32, two 16-bit counters (i=2p lo, i=2p+1 hi)
    unsigned negpk[8][2] = {};
    unsigned long long hitacc = 0ull;

    // ---- prologue: prefetch chunk r0's B-gather u32s and (r0, mt0) A-frags ----
    unsigned pb[16];
    ISSUE_B(r0, pb);
    short8 ac0 = __builtin_bit_cast(short8, aw[AIDX(r0, 0)]);
    short8 ac1 = __builtin_bit_cast(short8, aw[AIDX(r0, 0) + 64]);

    for (int r = r0; r < rend; ++r) {
        // ---- repack current B (split packed hi|lo) via v_perm_b32 ----
        short8 bhi[2], blo[2];
        #pragma unroll
        for (int kh2 = 0; kh2 < 2; ++kh2) {
            union { unsigned d[4]; short8 v; } H, L;
            #pragma unroll
            for (int p = 0; p < 4; ++p) {
                unsigned ua = pb[kh2 * 8 + 2 * p], ub = pb[kh2 * 8 + 2 * p + 1];
                H.d[p] = __builtin_amdgcn_perm(ub, ua, 0x05040100u); // ua.lo | ub.lo<<16
                L.d[p] = __builtin_amdgcn_perm(ub, ua, 0x07060302u); // ua.hi | ub.hi<<16
            }
            bhi[kh2] = H.v;
            blo[kh2] = L.v;
        }

        // issue next chunk's gathers, branchless (last r harmlessly reloads)
        const int rn = (r + 1 < rend) ? r + 1 : r;
        ISSUE_B(rn, pb);

        // ---- 8 m-tiles, fully branchless; rolling depth-1 A-pair prefetch ----
        f32x4 accs[8];
        #pragma unroll
        for (int mt = 0; mt < 8; ++mt) {
            const int pn = (mt == 7) ? AIDX(rn, 0) : AIDX(r, mt + 1);
            short8 an0 = __builtin_bit_cast(short8, aw[pn]);
            short8 an1 = __builtin_bit_cast(short8, aw[pn + 64]);

            f32x4 acc = {0.0f, 0.0f, 0.0f, 0.0f};
            acc = __builtin_amdgcn_mfma_f32_16x16x32_bf16(ac0, bhi[0], acc, 0, 0, 0);
            acc = __builtin_amdgcn_mfma_f32_16x16x32_bf16(ac1, bhi[1], acc, 0, 0, 0);
            acc = __builtin_amdgcn_mfma_f32_16x16x32_bf16(ac0, blo[0], acc, 0, 0, 0);
            acc = __builtin_amdgcn_mfma_f32_16x16x32_bf16(ac1, blo[1], acc, 0, 0, 0);
            accs[mt] = acc;
            #pragma unroll
            for (int p = 0; p < 2; ++p) {
                unsigned sb0 = __float_as_uint(acc[2 * p]) >> 31;
                unsigned sb1 = __float_as_uint(acc[2 * p + 1]) >> 31;
                negpk[mt][p] += sb0 + (sb1 << 16);
                hitacc |= __ballot(__builtin_fabsf(acc[2 * p]) < TAU);
                hitacc |= __ballot(__builtin_fabsf(acc[2 * p + 1]) < TAU);
            }
            ac0 = an0;
            ac1 = an1;
        }

        // ---- one rare cold branch per chunk: queue hits (per-lane id rebuilt) ----
        if (hitacc) {
            #pragma unroll
            for (int mt = 0; mt < 8; ++mt)
                #pragma unroll
                for (int i = 0; i < 4; ++i) {
                    float s = accs[mt][i];
                    if (__builtin_fabsf(s) < TAU) {
                        unsigned ge = (__float_as_uint(s) >> 31) ^ 1u;   // match negpk
                        unsigned idx = atomicAdd(&hitcnt, 1u);           // LDS atomic: rare
                        if (idx < (unsigned)HITCAP) {
                            unsigned m = (unsigned)(g * 128 + mt * 16 + quad * 4 + i);
                            unsigned n = (unsigned)(n0 + nt * 16 + nl);
                            hitbuf[idx] = n | ((unsigned)r << 14) | (m << 19)
                                            | (ge << 27);
                        }
                    }
                }
            hitacc = 0ull;
        }
    }

    // ---- merge kz quarters via LDS; kz=0 waves store final counts ----
    if (kz != 0) {
        #pragma unroll
        for (int mt = 0; mt < 8; ++mt) {
            unsigned c0 = negpk[mt][0] & 0xffffu, c1 = negpk[mt][0] >> 16;
            unsigned c2 = negpk[mt][1] & 0xffffu, c3 = negpk[mt][1] >> 16;
            red_s[kz - 1][nt][lane][mt] = c0 | (c1 << 8) | (c2 << 16) | (c3 << 24);
        }
    }
    __syncthreads();
    if (kz == 0) {
        const int n = n0 + nt * 16 + nl;
        const int p = n & 1023;
        #pragma unroll
        for (int mt = 0; mt < 8; ++mt) {
            unsigned pk1 = red_s[0][nt][lane][mt];
            unsigned pk2 = red_s[1][nt][lane][mt];
            unsigned pk3 = red_s[2][nt][lane][mt];
            unsigned tot0 = (negpk[mt][0] & 0xffffu) + (pk1 & 255u) + (pk2 & 255u) + (pk3 & 255u);
            unsigned tot1 = (negpk[mt][0] >> 16) + ((pk1 >> 8) & 255u) + ((pk2 >> 8) & 255u) + ((pk3 >> 8) & 255u);
            unsigned tot2 = (negpk[mt][1] & 0xffffu) + ((pk1 >> 16) & 255u) + ((pk2 >> 16) & 255u) + ((pk3 >> 16) & 255u);
            unsigned tot3 = (negpk[mt][1] >> 16) + (pk1 >> 24) + (pk2 >> 24) + (pk3 >> 24);
            int mb = g * 128 + mt * 16 + quad * 4;
            size_t obase = ((size_t)(b * 256 + mb)) << 10;
            out[obase + p]                = (float)(18u - tot0);
            out[obase + (1ull << 10) + p] = (float)(18u - tot1);
            out[obase + (2ull << 10) + p] = (float)(18u - tot2);
            out[obase + (3ull << 10) + p] = (float)(18u - tot3);
        }
    }

    // ---- in-block fixup of this block's own hits (R4 k_fix body, verbatim math) ----
    __syncthreads();
    unsigned tot = hitcnt;
    if (tot > (unsigned)HITCAP) tot = (unsigned)HITCAP;
    for (unsigned i = t; i < tot; i += 512) {
        unsigned u = hitbuf[i];
        int n = u & 16383;
        int r = (u >> 14) & 31;
        int m = (u >> 19) & 255;
        int bit = (u >> 27) & 1;
        int bb = n >> 10, p = n & 1023, y = p >> 5, x = p & 31;
        const float* ib = inp + (size_t)bb * (128 * 32 * 32);
        const float* wp = weight + (size_t)m * 1152;
        float s = 0.0f;
        int d = r * 64;
        for (int c = 0; c < 64; ++c, ++d) {
            int ci = d / 9, rem = d - ci * 9;
            int kh = rem / 3, kw = rem - kh * 3;
            int yy = y + kh - 1, xx = x + kw - 1;
            float xv = 0.0f;
            if ((unsigned)yy < 32u && (unsigned)xx < 32u)
                xv = ib[(ci * 32 + yy) * 32 + xx];
            float q = rintf(__fmul_rn(wp[d], sc));
            q = fminf(fmaxf(q, -7.0f), 7.0f);
            s = __fadd_rn(s, __fmul_rn(xv, q));
        }
        int nb = (s >= 0.0f) ? 1 : 0;
        if (nb != bit)
            atomicAdd(&out[(((size_t)(bb * 256 + m)) << 10) + p], nb ? 1.0f : -1.0f);
    }
}

extern "C" void kernel_launch(void* const* d_in, const int* in_sizes, int n_in,
                              void* d_out, int out_size, void* d_ws, size_t ws_size,
                              hipStream_t stream) {
    const float* inp    = (const float*)d_in[0];   // [16,128,32,32]
    const float* weight = (const float*)d_in[1];   // [256,128,3,3]
    float* out = (float*)d_out;                    // [16,256,32,32]

    char* ws = (char*)d_ws;
    float*    pmin  = (float*)(ws + 0);
    float*    pmax  = (float*)(ws + 256);
    uv4*      wqb   = (uv4*)(ws + 1024);          // 589,824 B
    unsigned* xpk   = (unsigned*)(ws + 590848);   // 9,469,952 B

    k_prep<<<2112, 256, 0, stream>>>(weight, inp, pmin, pmax, xpk);
    k_quantb<<<144, 256, 0, stream>>>(weight, pmin, pmax, wqb);

    dim3 grid(512, 2);   // (N/32, M/128); 512-thread blocks, 4-way split-K in-block
    k_main<<<grid, 512, 0, stream>>>(xpk, wqb, inp, weight, pmin, pmax, out);
}

// Round 7
// 123.352 us; speedup vs baseline: 1.5671x; 1.1399x over previous
//
#include <hip/hip_runtime.h>

// ONN conv2d: B=16, Cin=128, H=W=32, Cout=256, k=3 (pad=1, stride=1)
// N=16384 positions, D=1152=18*64 chunks of VEC=64, M=256.
// out[n,m] = sum_r sign01( dot_c( x[n,64r+c], wq[64r+c,m] ) )
// wq = clamp(rintf(w*scale), -7, 7), scale = fl32(15/(fl32(max-min)+1e-9f))
//
// Main path: bf16 MFMA with x split hi/lo (w int4 exact in bf16).
// |mfma_dot - ref_fp32_chain| < ~2e-3; dots with |s| < TAU=0.03 recomputed
// bit-exactly (sequential fp32, ascending c, separate mul/add -- R4 body).
// R3->R4: per-dot global atomics -> per-block LDS queue (611 -> 93 us).
// R5 FAILED: rewritten k_fix body flipped a sign; reverted (proven R4 body).
// R6: k_fix grid 64->512. R7: barrier-free gather k_main.
// R8: depth-1 B prefetch + fix folded into tail (64.3 us k_main).
// R9 FAILED (101 us): split-K GLOBAL atomics blew HBM; bounds squeezed regs.
// R10: branchless hot chunk, one cold handler/chunk (63.0 us; VGPR 64).
// R11: 128m/wave amortization + sign-VALU trim; grid (256,2) starved
//      occupancy (2 waves/SIMD) -> 73 us despite VALUBusy 47->25.
// R12: in-block 2-way split-K (512 thr = 4nt x 2kz, LDS merge): 52.7 us.
//      VGPR 64, Occ 26.6. Budget: VALU 15.8us + MFMA 7us + ~30us IDLE.
// R13 FAILED (122 us): launch_bounds(768,6) -> VGPR 40 -> scratch spill
//      (WRITE 294MB). Lesson: never request waves beyond the proven alloc.
// R14 FAILED (73 us): grid-driven occupancy (2nt x 4kz, 1024 blocks):
//      occupancy flat (~2 blk/CU cap anyway), FETCH 25->63MB (halo +
//      L2 re-fetch from halved n-tiles). Grid lever exhausted.
// R15: attack the idle directly on the R12 base. (a) A-fragment prefetch
//      ring depth-4: mt-step k consumes slot k&3, reloads it with the
//      pair needed 4 steps later (issue-to-use 40 -> ~200cyc, matching
//      L2 latency; the 8x-per-chunk exposed A-stall was the dominant
//      idle). +32 VGPR, still <=128 (4 waves/SIMD). (b) XCD-bijective
//      swizzle: each XCD gets 64 consecutive blocks, one shared g-half
//      (295KB wqb L2-resident) + contiguous n. All else R12-verbatim.

#define TAU 0.03f
#define HITCAP 2048

typedef short short8 __attribute__((ext_vector_type(8)));
typedef float f32x4 __attribute__((ext_vector_type(4)));
typedef unsigned int uv4 __attribute__((ext_vector_type(4)));

__device__ __forceinline__ unsigned short bf16rn(float v) {
    unsigned u = __float_as_uint(v);
    unsigned r = u + 0x7fffu + ((u >> 16) & 1u);
    return (unsigned short)(r >> 16);
}

// ---------------- prep: weight min/max partials (blocks 0..63) +
//                  zero-padded hi/lo bf16 planes (blocks 64..2111) ----------------
__global__ __launch_bounds__(256) void k_prep(const float* __restrict__ w,
                                              const float* __restrict__ inp,
                                              float* __restrict__ pmin,
                                              float* __restrict__ pmax,
                                              unsigned* __restrict__ xpk) {
    if (blockIdx.x < 64) {
        int tid = blockIdx.x * 256 + threadIdx.x;
        float vmin = 1e30f, vmax = -1e30f;
        for (int i = tid; i < 294912; i += 64 * 256) {
            float v = w[i];
            vmin = fminf(vmin, v);
            vmax = fmaxf(vmax, v);
        }
        #pragma unroll
        for (int off = 32; off > 0; off >>= 1) {
            vmin = fminf(vmin, __shfl_down(vmin, off, 64));
            vmax = fmaxf(vmax, __shfl_down(vmax, off, 64));
        }
        __shared__ float smin[4], smax[4];
        int wave = threadIdx.x >> 6;
        if ((threadIdx.x & 63) == 0) { smin[wave] = vmin; smax[wave] = vmax; }
        __syncthreads();
        if (threadIdx.x == 0) {
            #pragma unroll
            for (int i = 1; i < 4; i++) {
                vmin = fminf(vmin, smin[i]);
                vmax = fmaxf(vmax, smax[i]);
            }
            pmin[blockIdx.x] = vmin;
            pmax[blockIdx.x] = vmax;
        }
    } else {
        int bc = blockIdx.x - 64;              // b*128 + cin (2048)
        const float* src = inp + (size_t)bc * 1024;
        unsigned* dst = xpk + (size_t)bc * 1156;
        #pragma unroll
        for (int i = 0; i < 5; ++i) {
            int idx = threadIdx.x + i * 256;
            if (idx < 1156) {
                int yy = idx / 34, xx = idx - yy * 34;
                float v = 0.0f;
                int ys = yy - 1, xs_ = xx - 1;
                if ((unsigned)ys < 32u && (unsigned)xs_ < 32u) v = src[ys * 32 + xs_];
                unsigned short h = bf16rn(v);
                float hf = __uint_as_float((unsigned)h << 16);
                unsigned short l = bf16rn(v - hf);
                dst[idx] = (unsigned)h | ((unsigned)l << 16);
            }
        }
    }
}

// block-local scale from the 64 partials (identical fp32 op sequence everywhere)
__device__ __forceinline__ float block_scale(const float* pmin, const float* pmax,
                                             float* sca_lds) {
    int t = threadIdx.x;
    if (t < 64) {
        float vmin = pmin[t];
        float vmax = pmax[t];
        #pragma unroll
        for (int off = 32; off > 0; off >>= 1) {
            vmin = fminf(vmin, __shfl_down(vmin, off, 64));
            vmax = fmaxf(vmax, __shfl_down(vmax, off, 64));
        }
        if (t == 0) {
            float tt = __fadd_rn(__fsub_rn(vmax, vmin), 1e-9f);
            *sca_lds = __fdiv_rn(15.0f, tt);
        }
    }
    __syncthreads();
    return *sca_lds;
}

// ---------------- prep: quantize weights into MFMA A-fragment order ----------------
// slot = ((g*18 + r)*8 + mt*2 + khalf)*64 + lane ; 16B per slot (8 bf16, k ascending)
// value(lane, j) = wq[d = 64r + khalf*32 + (lane>>4)*8 + j][m = g*64 + mt*16 + (lane&15)]
__global__ __launch_bounds__(256) void k_quantb(const float* __restrict__ w,
                                                const float* __restrict__ pmin,
                                                const float* __restrict__ pmax,
                                                uv4* __restrict__ wqb) {
    __shared__ float sca;
    float s = block_scale(pmin, pmax, &sca);
    int slot = blockIdx.x * 256 + threadIdx.x;   // 36864 total
    int lane = slot & 63;
    int sub = slot >> 6;
    int khalf = sub & 1;
    int mt = (sub >> 1) & 3;
    int gr = sub >> 3;                 // g*18 + r
    int g = gr / 18, r = gr - g * 18;
    int m = g * 64 + mt * 16 + (lane & 15);
    int dbase = r * 64 + khalf * 32 + (lane >> 4) * 8;
    const float* wp = w + (size_t)m * 1152 + dbase;
    unsigned o[4];
    #pragma unroll
    for (int p = 0; p < 4; ++p) {
        float q0 = rintf(__fmul_rn(wp[2 * p], s));
        float q1 = rintf(__fmul_rn(wp[2 * p + 1], s));
        q0 = fminf(fmaxf(q0, -7.0f), 7.0f);
        q1 = fminf(fmaxf(q1, -7.0f), 7.0f);
        o[p] = (unsigned)bf16rn(q0) | ((unsigned)bf16rn(q1) << 16);
    }
    uv4 v; v.x = o[0]; v.y = o[1]; v.z = o[2]; v.w = o[3];
    wqb[slot] = v;
}

// gather: uniform SGPR base + per-lane 32-bit byte offset (xdelta + plane ofs)
#define XLD(o) (*reinterpret_cast<const unsigned*>(xpkB + (xdelta + (unsigned)(o))))

// issue the 16 B-gather u32 loads for chunk rr into dst[16]
// (byte offsets via 4x ds_read_b128; q2<8 -> khalf0, q2>=8 -> khalf1)
#define ISSUE_B(rr, dst) do {                                                  \
    const int4* _oa = reinterpret_cast<const int4*>(&ofs_s[(rr) * 64 + quad * 8]); \
    int4 _o0 = _oa[0], _o1 = _oa[1];                                           \
    const int4* _ob = reinterpret_cast<const int4*>(&ofs_s[(rr) * 64 + 32 + quad * 8]); \
    int4 _o2 = _ob[0], _o3 = _ob[1];                                           \
    dst[0] = XLD(_o0.x); dst[1] = XLD(_o0.y); dst[2] = XLD(_o0.z); dst[3] = XLD(_o0.w); \
    dst[4] = XLD(_o1.x); dst[5] = XLD(_o1.y); dst[6] = XLD(_o1.z); dst[7] = XLD(_o1.w); \
    dst[8] = XLD(_o2.x); dst[9] = XLD(_o2.y); dst[10] = XLD(_o2.z); dst[11] = XLD(_o2.w); \
    dst[12] = XLD(_o3.x); dst[13] = XLD(_o3.y); dst[14] = XLD(_o3.z); dst[15] = XLD(_o3.w); \
} while (0)

// A-fragment slot index for (chunk rr, m-tile mm) at this lane (mm in 0..7;
// wqb layout has 4 original g-groups of 4 mt, our 128m half spans 2 groups)
#define AIDX(rr, mm) ((((mm) >> 2) * 9216) + (rr) * 512 + (((mm) & 3) * 128))

// one m-tile step: 4 MFMAs on slot pair, then reload slot with the pair
// needed 4 mt-steps later (prefetch ring, issue-to-use ~200cyc)
#define MT_STEP(mt, sA, sB, pr, pm) do {                                        \
    f32x4 acc = {0.0f, 0.0f, 0.0f, 0.0f};                                       \
    acc = __builtin_amdgcn_mfma_f32_16x16x32_bf16(sA, bhi[0], acc, 0, 0, 0);    \
    acc = __builtin_amdgcn_mfma_f32_16x16x32_bf16(sB, bhi[1], acc, 0, 0, 0);    \
    acc = __builtin_amdgcn_mfma_f32_16x16x32_bf16(sA, blo[0], acc, 0, 0, 0);    \
    acc = __builtin_amdgcn_mfma_f32_16x16x32_bf16(sB, blo[1], acc, 0, 0, 0);    \
    sA = __builtin_bit_cast(short8, aw[AIDX(pr, pm)]);                          \
    sB = __builtin_bit_cast(short8, aw[AIDX(pr, pm) + 64]);                     \
    accs[mt] = acc;                                                             \
    _Pragma("unroll")                                                           \
    for (int p = 0; p < 2; ++p) {                                               \
        unsigned sb0 = __float_as_uint(acc[2 * p]) >> 31;                       \
        unsigned sb1 = __float_as_uint(acc[2 * p + 1]) >> 31;                   \
        negpk[mt][p] += sb0 + (sb1 << 16);                                      \
        hitacc |= __ballot(__builtin_fabsf(acc[2 * p]) < TAU);                  \
        hitacc |= __ballot(__builtin_fabsf(acc[2 * p + 1]) < TAU);              \
    }                                                                           \
} while (0)

// ---------------- main: in-block split-K gather GEMM (512 thr) + fix ----------------
// 8 waves = 4 n-tiles x 2 kz halves; each wave: 16n x 128m x 9 chunks.
// kz=1 waves deposit packed negcnt in LDS; kz=0 waves merge + store.
__global__ __launch_bounds__(512, 4) void k_main(const unsigned* __restrict__ xpk,
                                                 const uv4* __restrict__ wqb,
                                                 const float* __restrict__ inp,
                                                 const float* __restrict__ weight,
                                                 const float* __restrict__ pmin,
                                                 const float* __restrict__ pmax,
                                                 float* __restrict__ out) {
    __shared__ alignas(16) int ofs_s[1152]; // BYTE plane offset per k: (cin*1156+kh*34+kw)*4
    __shared__ unsigned hitbuf[HITCAP];
    __shared__ unsigned red_s[4][64][9];    // [nt][lane][mt] packed bytes (+pad col)
    __shared__ unsigned hitcnt;
    __shared__ float sca;

    const int t = threadIdx.x;
    if (t == 0) hitcnt = 0u;
    float sc = block_scale(pmin, pmax, &sca);   // also covers the hitcnt init barrier
    for (int k = t; k < 1152; k += 512) {
        int cin = k / 9;
        int rem = k - cin * 9;
        int kh = rem / 3;
        int kw = rem - kh * 3;
        ofs_s[k] = (cin * 1156 + kh * 34 + kw) * 4;
    }
    __syncthreads();

    // XCD-bijective swizzle: 512 blocks, 8 XCDs, 64 consecutive per XCD;
    // each XCD shares one g-half (wqb 295KB L2-resident) + contiguous n.
    const int lin = (int)(blockIdx.y * gridDim.x + blockIdx.x);   // 0..511
    const int nlin = (lin & 7) * 64 + (lin >> 3);
    const int g = nlin >> 8;           // 128-m half: m in [g*128, g*128+128)
    const int n0 = (nlin & 255) * 64;

    const int lane = t & 63;
    const int wv8 = t >> 6;            // 0..7
    const int nt = wv8 >> 1;           // n-tile 0..3
    const int kz = wv8 & 1;            // K half: chunks [kz*9, kz*9+9)
    const int quad = lane >> 4;
    const int nl = lane & 15;
    const int b = n0 >> 10;
    const int r0 = kz * 9, rend = r0 + 9;

    // wave's image-position base (16 consecutive positions within one row)
    const int sy_w = ((n0 & 1023) >> 5) + (nt >> 1);
    const int col0 = (nt & 1) * 16;
    const char* __restrict__ xpkB = (const char*)xpk;   // uniform base (SGPR)
    const unsigned xdelta =
        ((unsigned)b * (128u * 1156u) + (unsigned)(sy_w * 34 + col0 + nl)) * 4u;
    const uv4* __restrict__ aw = wqb + (size_t)g * (2 * 18 * 512) + lane;

    // negcnt packed: [mt][pair] u32, two 16-bit counters (i=2p lo, i=2p+1 hi)
    unsigned negpk[8][2] = {};
    unsigned long long hitacc = 0ull;

    // ---- prologue: prefetch chunk r0's B-gathers and the first 4 A-pairs ----
    unsigned pb[16];
    ISSUE_B(r0, pb);
    short8 a0A = __builtin_bit_cast(short8, aw[AIDX(r0, 0)]);
    short8 a0B = __builtin_bit_cast(short8, aw[AIDX(r0, 0) + 64]);
    short8 a1A = __builtin_bit_cast(short8, aw[AIDX(r0, 1)]);
    short8 a1B = __builtin_bit_cast(short8, aw[AIDX(r0, 1) + 64]);
    short8 a2A = __builtin_bit_cast(short8, aw[AIDX(r0, 2)]);
    short8 a2B = __builtin_bit_cast(short8, aw[AIDX(r0, 2) + 64]);
    short8 a3A = __builtin_bit_cast(short8, aw[AIDX(r0, 3)]);
    short8 a3B = __builtin_bit_cast(short8, aw[AIDX(r0, 3) + 64]);

    for (int r = r0; r < rend; ++r) {
        // ---- repack current B (split packed hi|lo) via v_perm_b32 ----
        short8 bhi[2], blo[2];
        #pragma unroll
        for (int kh2 = 0; kh2 < 2; ++kh2) {
            union { unsigned d[4]; short8 v; } H, L;
            #pragma unroll
            for (int p = 0; p < 4; ++p) {
                unsigned ua = pb[kh2 * 8 + 2 * p], ub = pb[kh2 * 8 + 2 * p + 1];
                H.d[p] = __builtin_amdgcn_perm(ub, ua, 0x05040100u); // ua.lo | ub.lo<<16
                L.d[p] = __builtin_amdgcn_perm(ub, ua, 0x07060302u); // ua.hi | ub.hi<<16
            }
            bhi[kh2] = H.v;
            blo[kh2] = L.v;
        }

        // issue next chunk's gathers, branchless (last r harmlessly reloads)
        const int rn = (r + 1 < rend) ? r + 1 : r;
        ISSUE_B(rn, pb);

        // ---- 8 m-tiles, branchless; depth-4 A-pair prefetch ring ----
        f32x4 accs[8];
        MT_STEP(0, a0A, a0B, r, 4);
        MT_STEP(1, a1A, a1B, r, 5);
        MT_STEP(2, a2A, a2B, r, 6);
        MT_STEP(3, a3A, a3B, r, 7);
        MT_STEP(4, a0A, a0B, rn, 0);
        MT_STEP(5, a1A, a1B, rn, 1);
        MT_STEP(6, a2A, a2B, rn, 2);
        MT_STEP(7, a3A, a3B, rn, 3);

        // ---- one rare cold branch per chunk: queue hits (per-lane id rebuilt) ----
        if (hitacc) {
            #pragma unroll
            for (int mt = 0; mt < 8; ++mt)
                #pragma unroll
                for (int i = 0; i < 4; ++i) {
                    float s = accs[mt][i];
                    if (__builtin_fabsf(s) < TAU) {
                        unsigned ge = (__float_as_uint(s) >> 31) ^ 1u;   // match negpk
                        unsigned idx = atomicAdd(&hitcnt, 1u);           // LDS atomic: rare
                        if (idx < (unsigned)HITCAP) {
                            unsigned m = (unsigned)(g * 128 + mt * 16 + quad * 4 + i);
                            unsigned n = (unsigned)(n0 + nt * 16 + nl);
                            hitbuf[idx] = n | ((unsigned)r << 14) | (m << 19)
                                            | (ge << 27);
                        }
                    }
                }
            hitacc = 0ull;
        }
    }

    // ---- merge kz halves via LDS; kz=0 waves store final counts ----
    if (kz == 1) {
        #pragma unroll
        for (int mt = 0; mt < 8; ++mt) {
            unsigned c0 = negpk[mt][0] & 0xffffu, c1 = negpk[mt][0] >> 16;
            unsigned c2 = negpk[mt][1] & 0xffffu, c3 = negpk[mt][1] >> 16;
            red_s[nt][lane][mt] = c0 | (c1 << 8) | (c2 << 16) | (c3 << 24);
        }
    }
    __syncthreads();
    if (kz == 0) {
        const int n = n0 + nt * 16 + nl;
        const int p = n & 1023;
        #pragma unroll
        for (int mt = 0; mt < 8; ++mt) {
            unsigned pk = red_s[nt][lane][mt];
            unsigned tot0 = (negpk[mt][0] & 0xffffu) + (pk & 255u);
            unsigned tot1 = (negpk[mt][0] >> 16) + ((pk >> 8) & 255u);
            unsigned tot2 = (negpk[mt][1] & 0xffffu) + ((pk >> 16) & 255u);
            unsigned tot3 = (negpk[mt][1] >> 16) + (pk >> 24);
            int mb = g * 128 + mt * 16 + quad * 4;
            size_t obase = ((size_t)(b * 256 + mb)) << 10;
            out[obase + p]                = (float)(18u - tot0);
            out[obase + (1ull << 10) + p] = (float)(18u - tot1);
            out[obase + (2ull << 10) + p] = (float)(18u - tot2);
            out[obase + (3ull << 10) + p] = (float)(18u - tot3);
        }
    }

    // ---- in-block fixup of this block's own hits (R4 k_fix body, verbatim math) ----
    __syncthreads();
    unsigned tot = hitcnt;
    if (tot > (unsigned)HITCAP) tot = (unsigned)HITCAP;
    for (unsigned i = t; i < tot; i += 512) {
        unsigned u = hitbuf[i];
        int n = u & 16383;
        int r = (u >> 14) & 31;
        int m = (u >> 19) & 255;
        int bit = (u >> 27) & 1;
        int bb = n >> 10, p = n & 1023, y = p >> 5, x = p & 31;
        const float* ib = inp + (size_t)bb * (128 * 32 * 32);
        const float* wp = weight + (size_t)m * 1152;
        float s = 0.0f;
        int d = r * 64;
        for (int c = 0; c < 64; ++c, ++d) {
            int ci = d / 9, rem = d - ci * 9;
            int kh = rem / 3, kw = rem - kh * 3;
            int yy = y + kh - 1, xx = x + kw - 1;
            float xv = 0.0f;
            if ((unsigned)yy < 32u && (unsigned)xx < 32u)
                xv = ib[(ci * 32 + yy) * 32 + xx];
            float q = rintf(__fmul_rn(wp[d], sc));
            q = fminf(fmaxf(q, -7.0f), 7.0f);
            s = __fadd_rn(s, __fmul_rn(xv, q));
        }
        int nb = (s >= 0.0f) ? 1 : 0;
        if (nb != bit)
            atomicAdd(&out[(((size_t)(bb * 256 + m)) << 10) + p], nb ? 1.0f : -1.0f);
    }
}

extern "C" void kernel_launch(void* const* d_in, const int* in_sizes, int n_in,
                              void* d_out, int out_size, void* d_ws, size_t ws_size,
                              hipStream_t stream) {
    const float* inp    = (const float*)d_in[0];   // [16,128,32,32]
    const float* weight = (const float*)d_in[1];   // [256,128,3,3]
    float* out = (float*)d_out;                    // [16,256,32,32]

    char* ws = (char*)d_ws;
    float*    pmin  = (float*)(ws + 0);
    float*    pmax  = (float*)(ws + 256);
    uv4*      wqb   = (uv4*)(ws + 1024);          // 589,824 B
    unsigned* xpk   = (unsigned*)(ws + 590848);   // 9,469,952 B

    k_prep<<<2112, 256, 0, stream>>>(weight, inp, pmin, pmax, xpk);
    k_quantb<<<144, 256, 0, stream>>>(weight, pmin, pmax, wqb);

    dim3 grid(256, 2);   // (N/64, M/128); 512-thread blocks, split-K in-block
    k_main<<<grid, 512, 0, stream>>>(xpk, wqb, inp, weight, pmin, pmax, out);
}